// Round 3
// baseline (170.575 us; speedup 1.0000x reference)
//
#include <hip/hip_runtime.h>

// Shape-matching constraint projection, rot == Identity (the reference's
// SVD-derived rotation Vh^T @ Vh is identity up to SVD orthogonality noise;
// U and s are discarded).
//
//   com_c     = sum_p m*pred / sum_p m          (P=16 particles/constraint)
//   delta_pos = (V_w * (init - (pred - com))) / V_compliance
//   out[idx]  = V_predict[idx] + delta_pos ;  L_last passes through.
//
// R2: C_shape is arange(N) (identity permutation, per setup_inputs). Fast
// path streams EVERYTHING as coalesced float4 (16B/lane) with addresses from
// the thread id -> no idx->gather dependence, max bytes-in-flight per load
// slot (R0/R1 showed a ~2 TB/s cap from outstanding-miss capacity with
// dword/dwordx3 gathers). Optimistic idx check keeps general correctness:
// wave-uniform never-taken fallback does the true gather/scatter.

__global__ __launch_bounds__(256) void shape_match_kernel(
    const float* __restrict__ V_predict,
    const float* __restrict__ L_last,
    const float* __restrict__ V_w,
    const float* __restrict__ V_mass,
    const int*   __restrict__ C_shape,
    const float* __restrict__ C_init,
    const float* __restrict__ V_comp,
    float*       __restrict__ out,
    float*       __restrict__ outL,
    int nquads, int work_blocks, int l_elems)
{
    if ((int)blockIdx.x >= work_blocks) {
        // ---- L_last passthrough (float4 copy) ----
        int i = (blockIdx.x - work_blocks) * blockDim.x + threadIdx.x;
        int n4 = l_elems >> 2;
        if (i < n4)
            reinterpret_cast<float4*>(outL)[i] =
                reinterpret_cast<const float4*>(L_last)[i];
        if (i == 0)
            for (int r = n4 << 2; r < l_elems; ++r) outL[r] = L_last[r];
        return;
    }

    const int t = blockIdx.x * blockDim.x + threadIdx.x;  // quad id
    if (t >= nquads) return;
    const int gp0 = t << 2;   // first particle slot of this quad

    // ---- streaming loads (all dwordx4, addresses independent of idx) ----
    const float4* pp = reinterpret_cast<const float4*>(V_predict) + (size_t)t * 3;
    float4 pa = pp[0], pb = pp[1], pc = pp[2];

    const float4* ip = reinterpret_cast<const float4*>(C_init) + (size_t)t * 3;
    const float4 ia = ip[0], ib = ip[1], ic = ip[2];

    float4 m4 = reinterpret_cast<const float4*>(V_mass)[t];
    float4 w4 = reinterpret_cast<const float4*>(V_w)[t];
    float4 k4 = reinterpret_cast<const float4*>(V_comp)[t];

    const int4 idx = reinterpret_cast<const int4*>(C_shape)[t];
    const bool ok = (idx.x == gp0) & (idx.y == gp0 + 1) &
                    (idx.z == gp0 + 2) & (idx.w == gp0 + 3);

    if (!ok) {
        // ---- general gather path (never taken for identity C_shape) ----
        const float3 q0 = *reinterpret_cast<const float3*>(V_predict + (size_t)idx.x * 3);
        const float3 q1 = *reinterpret_cast<const float3*>(V_predict + (size_t)idx.y * 3);
        const float3 q2 = *reinterpret_cast<const float3*>(V_predict + (size_t)idx.z * 3);
        const float3 q3 = *reinterpret_cast<const float3*>(V_predict + (size_t)idx.w * 3);
        pa = make_float4(q0.x, q0.y, q0.z, q1.x);
        pb = make_float4(q1.y, q1.z, q2.x, q2.y);
        pc = make_float4(q2.z, q3.x, q3.y, q3.z);
        m4 = make_float4(V_mass[idx.x], V_mass[idx.y], V_mass[idx.z], V_mass[idx.w]);
        w4 = make_float4(V_w[idx.x],    V_w[idx.y],    V_w[idx.z],    V_w[idx.w]);
        k4 = make_float4(V_comp[idx.x], V_comp[idx.y], V_comp[idx.z], V_comp[idx.w]);
    }

    // unpack particle positions
    const float p0x = pa.x, p0y = pa.y, p0z = pa.z;
    const float p1x = pa.w, p1y = pb.x, p1z = pb.y;
    const float p2x = pb.z, p2y = pb.w, p2z = pc.x;
    const float p3x = pc.y, p3y = pc.z, p3z = pc.w;

    // weighted partial sums over this thread's 4 particles
    float sx = m4.x * p0x + m4.y * p1x + m4.z * p2x + m4.w * p3x;
    float sy = m4.x * p0y + m4.y * p1y + m4.z * p2y + m4.w * p3y;
    float sz = m4.x * p0z + m4.y * p1z + m4.z * p2z + m4.w * p3z;
    float sm = m4.x + m4.y + m4.z + m4.w;

    // 2-step butterfly across the 4 threads of one constraint (16 particles)
    sx += __shfl_xor(sx, 1);
    sy += __shfl_xor(sy, 1);
    sz += __shfl_xor(sz, 1);
    sm += __shfl_xor(sm, 1);
    sx += __shfl_xor(sx, 2);
    sy += __shfl_xor(sy, 2);
    sz += __shfl_xor(sz, 2);
    sm += __shfl_xor(sm, 2);

    const float inv  = 1.0f / sm;
    const float comx = sx * inv;
    const float comy = sy * inv;
    const float comz = sz * inv;

    const float r0 = 1.0f / k4.x, r1 = 1.0f / k4.y,
                r2 = 1.0f / k4.z, r3 = 1.0f / k4.w;

    // o = p + (w*(init - p + com)) * (1/k)   (matches reference mul order)
    float4 oa, ob, oc;
    oa.x = p0x + (w4.x * (ia.x - p0x + comx)) * r0;
    oa.y = p0y + (w4.x * (ia.y - p0y + comy)) * r0;
    oa.z = p0z + (w4.x * (ia.z - p0z + comz)) * r0;
    oa.w = p1x + (w4.y * (ia.w - p1x + comx)) * r1;
    ob.x = p1y + (w4.y * (ib.x - p1y + comy)) * r1;
    ob.y = p1z + (w4.y * (ib.y - p1z + comz)) * r1;
    ob.z = p2x + (w4.z * (ib.z - p2x + comx)) * r2;
    ob.w = p2y + (w4.z * (ib.w - p2y + comy)) * r2;
    oc.x = p2z + (w4.z * (ic.x - p2z + comz)) * r2;
    oc.y = p3x + (w4.w * (ic.y - p3x + comx)) * r3;
    oc.z = p3y + (w4.w * (ic.z - p3y + comy)) * r3;
    oc.w = p3z + (w4.w * (ic.w - p3z + comz)) * r3;

    if (ok) {
        float4* op = reinterpret_cast<float4*>(out) + (size_t)t * 3;
        op[0] = oa; op[1] = ob; op[2] = oc;
    } else {
        // general scatter (never taken for identity C_shape)
        float* o = out;
        o[(size_t)idx.x*3+0] = oa.x; o[(size_t)idx.x*3+1] = oa.y; o[(size_t)idx.x*3+2] = oa.z;
        o[(size_t)idx.y*3+0] = oa.w; o[(size_t)idx.y*3+1] = ob.x; o[(size_t)idx.y*3+2] = ob.y;
        o[(size_t)idx.z*3+0] = ob.z; o[(size_t)idx.z*3+1] = ob.w; o[(size_t)idx.z*3+2] = oc.x;
        o[(size_t)idx.w*3+0] = oc.y; o[(size_t)idx.w*3+1] = oc.z; o[(size_t)idx.w*3+2] = oc.w;
    }
}

extern "C" void kernel_launch(void* const* d_in, const int* in_sizes, int n_in,
                              void* d_out, int out_size, void* d_ws, size_t ws_size,
                              hipStream_t stream)
{
    const float* V_predict = (const float*)d_in[0];
    const float* L_last    = (const float*)d_in[1];
    const float* V_w       = (const float*)d_in[2];
    const float* V_mass    = (const float*)d_in[3];
    const int*   C_shape   = (const int*)  d_in[4];
    const float* C_init    = (const float*)d_in[5];
    const float* V_comp    = (const float*)d_in[6];

    const int N     = in_sizes[0] / 3;   // vertices
    const int num_c = in_sizes[1];       // constraints (P fixed at 16)

    float* out  = (float*)d_out;
    float* outL = out + (size_t)N * 3;   // L_last output region

    const int block       = 256;
    const int nquads      = num_c * 4;                     // 4 particles/thread
    const int work_blocks = (nquads + block - 1) / block;
    const int n4          = (num_c + 3) / 4;               // float4 copy count
    const int l_blocks    = (n4 + block - 1) / block;

    shape_match_kernel<<<work_blocks + l_blocks, block, 0, stream>>>(
        V_predict, L_last, V_w, V_mass, C_shape, C_init, V_comp,
        out, outL, nquads, work_blocks, num_c);
}

// Round 4
// 166.559 us; speedup vs baseline: 1.0241x; 1.0241x over previous
//
#include <hip/hip_runtime.h>

// Shape-matching constraint projection, rot == Identity (the reference's
// SVD-derived rotation Vh^T @ Vh is identity up to SVD orthogonality noise;
// U and s are discarded).
//
//   com_c     = sum_p m*pred / sum_p m          (P=16 particles/constraint)
//   delta_pos = (V_w * (init - (pred - com))) / V_compliance
//   out[idx]  = V_predict[idx] + delta_pos ;  L_last passes through.
//
// R3: R0-R2 all plateaued at ~55us regardless of ILP/TLP/width. Shared
// defect: the fat float3 streams (pred/init/out, 115MB of 168MB) were read
// with 48B (or 12B) LANE STRIDE per instruction -> each dwordx4 spans 24
// cache lines instead of 8 (3x sector cost in TA/L1). Fix: wave-level LDS
// transpose. Each wave loads its 192-float4 tile with 3 unit-stride
// instructions (1KB contiguous per instr), bounces through LDS, reads back
// quad-local (48B LDS stride = 2-way bank alias = free). Output reversed.
// Wave-local only -> no barriers, just lgkmcnt fences (+sched_barrier, rule 18).

#define FENCE_LDS() do { \
    asm volatile("s_waitcnt lgkmcnt(0)" ::: "memory"); \
    __builtin_amdgcn_sched_barrier(0); \
} while (0)

__global__ __launch_bounds__(256) void shape_match_kernel(
    const float* __restrict__ V_predict,
    const float* __restrict__ L_last,
    const float* __restrict__ V_w,
    const float* __restrict__ V_mass,
    const int*   __restrict__ C_shape,
    const float* __restrict__ C_init,
    const float* __restrict__ V_comp,
    float*       __restrict__ out,
    float*       __restrict__ outL,
    int nquads, int work_blocks, int l_elems)
{
    __shared__ float4 lds[4][192];   // 3KB per wave, 12KB per block

    if ((int)blockIdx.x >= work_blocks) {
        // ---- L_last passthrough (float4 copy) ----
        int i = (blockIdx.x - work_blocks) * blockDim.x + threadIdx.x;
        int n4 = l_elems >> 2;
        if (i < n4)
            reinterpret_cast<float4*>(outL)[i] =
                reinterpret_cast<const float4*>(L_last)[i];
        if (i == 0)
            for (int r = n4 << 2; r < l_elems; ++r) outL[r] = L_last[r];
        return;
    }

    const int t = blockIdx.x * blockDim.x + threadIdx.x;  // quad id
    if (t >= nquads) return;
    const int lane = threadIdx.x & 63;
    const int wv   = threadIdx.x >> 6;
    const int waveQuad0 = t - lane;            // first quad of this wave
    const int waveWord  = waveQuad0 * 3;       // first float4-word of wave tile
    const int gp0 = t << 2;                    // first particle slot of quad

    // small streams: unit-stride 16B/lane, issue early
    const int4 idx = reinterpret_cast<const int4*>(C_shape)[t];
    float4 m4 = reinterpret_cast<const float4*>(V_mass)[t];
    float4 w4 = reinterpret_cast<const float4*>(V_w)[t];
    float4 k4 = reinterpret_cast<const float4*>(V_comp)[t];

    const bool ok = (idx.x == gp0) & (idx.y == gp0 + 1) &
                    (idx.z == gp0 + 2) & (idx.w == gp0 + 3);
    const bool full_wave = (waveQuad0 + 64 <= nquads);
    const bool fast = full_wave && __all(ok);

    float4 pa, pb, pc, ia, ib, ic;

    if (fast) {
        // ---- unit-stride plane loads: each instr = 1KB contiguous/wave ----
        const float4* Pw = reinterpret_cast<const float4*>(V_predict) + waveWord;
        const float4 q0 = Pw[lane], q1 = Pw[lane + 64], q2 = Pw[lane + 128];
        const float4* Iw = reinterpret_cast<const float4*>(C_init) + waveWord;
        const float4 r0 = Iw[lane], r1 = Iw[lane + 64], r2 = Iw[lane + 128];

        float4* L = lds[wv];
        // transpose pred: plane -> quad-local
        L[lane] = q0; L[lane + 64] = q1; L[lane + 128] = q2;
        FENCE_LDS();
        pa = L[lane * 3]; pb = L[lane * 3 + 1]; pc = L[lane * 3 + 2];
        FENCE_LDS();                       // reads done before overwrite (WAR)
        // transpose init (same buffer)
        L[lane] = r0; L[lane + 64] = r1; L[lane + 128] = r2;
        FENCE_LDS();
        ia = L[lane * 3]; ib = L[lane * 3 + 1]; ic = L[lane * 3 + 2];
    } else {
        // ---- general gather path (never taken for identity C_shape) ----
        const float3 q0 = *reinterpret_cast<const float3*>(V_predict + (size_t)idx.x * 3);
        const float3 q1 = *reinterpret_cast<const float3*>(V_predict + (size_t)idx.y * 3);
        const float3 q2 = *reinterpret_cast<const float3*>(V_predict + (size_t)idx.z * 3);
        const float3 q3 = *reinterpret_cast<const float3*>(V_predict + (size_t)idx.w * 3);
        pa = make_float4(q0.x, q0.y, q0.z, q1.x);
        pb = make_float4(q1.y, q1.z, q2.x, q2.y);
        pc = make_float4(q2.z, q3.x, q3.y, q3.z);
        const float4* ip = reinterpret_cast<const float4*>(C_init) + (size_t)t * 3;
        ia = ip[0]; ib = ip[1]; ic = ip[2];
        m4 = make_float4(V_mass[idx.x], V_mass[idx.y], V_mass[idx.z], V_mass[idx.w]);
        w4 = make_float4(V_w[idx.x],    V_w[idx.y],    V_w[idx.z],    V_w[idx.w]);
        k4 = make_float4(V_comp[idx.x], V_comp[idx.y], V_comp[idx.z], V_comp[idx.w]);
    }

    // unpack particle positions
    const float p0x = pa.x, p0y = pa.y, p0z = pa.z;
    const float p1x = pa.w, p1y = pb.x, p1z = pb.y;
    const float p2x = pb.z, p2y = pb.w, p2z = pc.x;
    const float p3x = pc.y, p3y = pc.z, p3z = pc.w;

    // weighted partial sums over this thread's 4 particles
    float sx = m4.x * p0x + m4.y * p1x + m4.z * p2x + m4.w * p3x;
    float sy = m4.x * p0y + m4.y * p1y + m4.z * p2y + m4.w * p3y;
    float sz = m4.x * p0z + m4.y * p1z + m4.z * p2z + m4.w * p3z;
    float sm = m4.x + m4.y + m4.z + m4.w;

    // 2-step butterfly across the 4 threads of one constraint (16 particles)
    sx += __shfl_xor(sx, 1);
    sy += __shfl_xor(sy, 1);
    sz += __shfl_xor(sz, 1);
    sm += __shfl_xor(sm, 1);
    sx += __shfl_xor(sx, 2);
    sy += __shfl_xor(sy, 2);
    sz += __shfl_xor(sz, 2);
    sm += __shfl_xor(sm, 2);

    const float inv  = 1.0f / sm;
    const float comx = sx * inv;
    const float comy = sy * inv;
    const float comz = sz * inv;

    const float r0s = 1.0f / k4.x, r1s = 1.0f / k4.y,
                r2s = 1.0f / k4.z, r3s = 1.0f / k4.w;

    // o = p + (w*(init - p + com)) * (1/k)   (matches reference mul order)
    float4 oa, ob, oc;
    oa.x = p0x + (w4.x * (ia.x - p0x + comx)) * r0s;
    oa.y = p0y + (w4.x * (ia.y - p0y + comy)) * r0s;
    oa.z = p0z + (w4.x * (ia.z - p0z + comz)) * r0s;
    oa.w = p1x + (w4.y * (ia.w - p1x + comx)) * r1s;
    ob.x = p1y + (w4.y * (ib.x - p1y + comy)) * r1s;
    ob.y = p1z + (w4.y * (ib.y - p1z + comz)) * r1s;
    ob.z = p2x + (w4.z * (ib.z - p2x + comx)) * r2s;
    ob.w = p2y + (w4.z * (ib.w - p2y + comy)) * r2s;
    oc.x = p2z + (w4.z * (ic.x - p2z + comz)) * r2s;
    oc.y = p3x + (w4.w * (ic.y - p3x + comx)) * r3s;
    oc.z = p3y + (w4.w * (ic.z - p3y + comy)) * r3s;
    oc.w = p3z + (w4.w * (ic.w - p3z + comz)) * r3s;

    if (fast) {
        float4* L = lds[wv];
        FENCE_LDS();                       // init-phase reads drained (WAR)
        // transpose out: quad-local -> plane
        L[lane * 3] = oa; L[lane * 3 + 1] = ob; L[lane * 3 + 2] = oc;
        FENCE_LDS();
        float4* Ow = reinterpret_cast<float4*>(out) + waveWord;
        Ow[lane]       = L[lane];
        Ow[lane + 64]  = L[lane + 64];
        Ow[lane + 128] = L[lane + 128];
    } else {
        // general scatter (never taken for identity C_shape)
        float* o = out;
        o[(size_t)idx.x*3+0] = oa.x; o[(size_t)idx.x*3+1] = oa.y; o[(size_t)idx.x*3+2] = oa.z;
        o[(size_t)idx.y*3+0] = oa.w; o[(size_t)idx.y*3+1] = ob.x; o[(size_t)idx.y*3+2] = ob.y;
        o[(size_t)idx.z*3+0] = ob.z; o[(size_t)idx.z*3+1] = ob.w; o[(size_t)idx.z*3+2] = oc.x;
        o[(size_t)idx.w*3+0] = oc.y; o[(size_t)idx.w*3+1] = oc.z; o[(size_t)idx.w*3+2] = oc.w;
    }
}

extern "C" void kernel_launch(void* const* d_in, const int* in_sizes, int n_in,
                              void* d_out, int out_size, void* d_ws, size_t ws_size,
                              hipStream_t stream)
{
    const float* V_predict = (const float*)d_in[0];
    const float* L_last    = (const float*)d_in[1];
    const float* V_w       = (const float*)d_in[2];
    const float* V_mass    = (const float*)d_in[3];
    const int*   C_shape   = (const int*)  d_in[4];
    const float* C_init    = (const float*)d_in[5];
    const float* V_comp    = (const float*)d_in[6];

    const int N     = in_sizes[0] / 3;   // vertices
    const int num_c = in_sizes[1];       // constraints (P fixed at 16)

    float* out  = (float*)d_out;
    float* outL = out + (size_t)N * 3;   // L_last output region

    const int block       = 256;
    const int nquads      = num_c * 4;                     // 4 particles/thread
    const int work_blocks = (nquads + block - 1) / block;
    const int n4          = (num_c + 3) / 4;               // float4 copy count
    const int l_blocks    = (n4 + block - 1) / block;

    shape_match_kernel<<<work_blocks + l_blocks, block, 0, stream>>>(
        V_predict, L_last, V_w, V_mass, C_shape, C_init, V_comp,
        out, outL, nquads, work_blocks, num_c);
}